// Round 8
// baseline (372.108 us; speedup 1.0000x reference)
//
#include <hip/hip_runtime.h>
#include <cmath>

// BlockwiseEarlyExitMamba: output depends only on feat[:,31,:] -> compute T=32 tokens.
#define TT 32
#define NTOK 512   // BATCH*TT
#define DM 256
#define DI 512

typedef float vf4 __attribute__((ext_vector_type(4)));

__device__ __forceinline__ float silu_(float x){ return x / (1.f + __expf(-x)); }

#define FMA16() do { \
  acc[0][0] += xv.x*wv.x; acc[0][1] += xv.x*wv.y; acc[0][2] += xv.x*wv.z; acc[0][3] += xv.x*wv.w; \
  acc[1][0] += xv.y*wv.x; acc[1][1] += xv.y*wv.y; acc[1][2] += xv.y*wv.z; acc[1][3] += xv.y*wv.w; \
  acc[2][0] += xv.z*wv.x; acc[2][1] += xv.z*wv.y; acc[2][2] += xv.z*wv.z; acc[2][3] += xv.z*wv.w; \
  acc[3][0] += xv.w*wv.x; acc[3][1] += xv.w*wv.y; acc[3][2] += xv.w*wv.z; acc[3][3] += xv.w*wv.w; \
} while(0)

// ---------- frontend: embed -> fusion GEMM (K=136) -> raw s0 (verified) ------
__global__ __launch_bounds__(128)
void k_front(const float* __restrict__ x,
             const float* __restrict__ ep, const float* __restrict__ ef,
             const float* __restrict__ ed,
             const float* __restrict__ plw, const float* __restrict__ plb,
             const float* __restrict__ piw, const float* __restrict__ pib,
             const float* __restrict__ fw,  const float* __restrict__ fb,
             float* __restrict__ s0)
{
  __shared__ float Xs[136*36];
  __shared__ float Ws[136*68];
  int bb = blockIdx.y;
  int n0 = blockIdx.x*64;
  int tid = threadIdx.x;
  for (int r = 0; r < 34; ++r){
    int idx = r*128 + tid;
    int t = idx & 31, j = idx >> 5;
    const float* xr = x + ((size_t)(bb*1024 + t))*5;
    float v;
    if      (j <  32){ int i = __float2int_rz(xr[0]); i = min(max(i,0),255); v = ep[i*32 + j]; }
    else if (j <  64){ v = xr[1]*plw[j-32] + plb[j-32]; }
    else if (j <  96){ int i = __float2int_rz(xr[2]); i = min(max(i,0),63);  v = ef[i*32 + (j-64)]; }
    else if (j < 128){ v = xr[3]*piw[j-96] + pib[j-96]; }
    else             { int i = __float2int_rz(xr[4]); i = min(max(i,0),1);   v = ed[i*8 + (j-128)]; }
    Xs[j*36 + t] = v;
  }
  {
    int c = tid >> 1, jh = tid & 1;
    const float4* src = (const float4*)(fw + (size_t)(n0 + c)*136 + jh*68);
    #pragma unroll
    for (int q = 0; q < 17; ++q){
      float4 v = src[q];
      int j = jh*68 + q*4;
      Ws[(j+0)*68 + c] = v.x; Ws[(j+1)*68 + c] = v.y;
      Ws[(j+2)*68 + c] = v.z; Ws[(j+3)*68 + c] = v.w;
    }
  }
  __syncthreads();
  int my = tid >> 4, nx = tid & 15;
  float acc[4][4] = {};
  #pragma unroll 4
  for (int k = 0; k < 136; ++k){
    float4 xv = *(const float4*)&Xs[k*36 + my*4];
    float4 wv = *(const float4*)&Ws[k*68 + nx*4];
    FMA16();
  }
  #pragma unroll
  for (int i = 0; i < 4; ++i){
    int t = my*4 + i;
    float4 o;
    o.x = acc[i][0] + fb[n0 + nx*4 + 0];
    o.y = acc[i][1] + fb[n0 + nx*4 + 1];
    o.z = acc[i][2] + fb[n0 + nx*4 + 2];
    o.w = acc[i][3] + fb[n0 + nx*4 + 3];
    *(float4*)&s0[(size_t)(bb*32 + t)*DM + n0 + nx*4] = o;
  }
}

// ---------------- L1: residual+LN + in_proj GEMM + conv/silu + x_proj partials
// grid 64 = (b = bid&15, s = bid>>4 in 0..3); 1024 thr; block owns x-dims
// [s*128,s*128+128) and z-dims [512+s*128, ...).
__global__ __launch_bounds__(1024, 1)
void k_L1(const float* __restrict__ wip,   // [1024][256] this layer
          const float* __restrict__ cwl, const float* __restrict__ cbl,
          const float* __restrict__ xpl,  // [48][512]
          const float* __restrict__ g, const float* __restrict__ bb,
          const float* __restrict__ featIn,   // prev post-LN (null for ly0)
          float* __restrict__ featOut,
          const float* __restrict__ parts,    // [4][512][256] or s0 [512][256]
          int fourparts,
          float* __restrict__ pxp,            // [64][48][32]
          float* __restrict__ xc, float* __restrict__ zs)
{
  extern __shared__ float lds[];
  float* featT = lds;            // [256][36]   9216
  float* S     = lds + 9216;     // 8448: LN red / W chunk [32][264] / xcl [32][133]
  float* sxz   = lds + 17664;    // [32][264]   8448
  int tid = threadIdx.x, bid = blockIdx.x;
  int b = bid & 15, s = bid >> 4;
  int w = tid >> 6, ln = tid & 63;

  // ---- stage + residual + LN (replicated over the 4 subs) ----
  {
    int t = tid & 31, ci = tid >> 5;   // ci 0..31 -> 8 channels
    size_t base = (size_t)(b*32 + t)*DM + ci*8;
    float v[8];
    {
      const float4* p0 = (const float4*)(parts + base);
      float4 u0 = p0[0], u1 = p0[1];
      v[0]=u0.x; v[1]=u0.y; v[2]=u0.z; v[3]=u0.w;
      v[4]=u1.x; v[5]=u1.y; v[6]=u1.z; v[7]=u1.w;
    }
    if (fourparts){
      #pragma unroll
      for (int q = 1; q < 4; ++q){
        const float4* pq = (const float4*)(parts + (size_t)q*NTOK*DM + base);
        float4 u0 = pq[0], u1 = pq[1];
        v[0]+=u0.x; v[1]+=u0.y; v[2]+=u0.z; v[3]+=u0.w;
        v[4]+=u1.x; v[5]+=u1.y; v[6]+=u1.z; v[7]+=u1.w;
      }
      const float4* pf = (const float4*)(featIn + base);
      float4 u0 = pf[0], u1 = pf[1];
      v[0]+=u0.x; v[1]+=u0.y; v[2]+=u0.z; v[3]+=u0.w;
      v[4]+=u1.x; v[5]+=u1.y; v[6]+=u1.z; v[7]+=u1.w;
    }
    float sm = 0.f, sq = 0.f;
    #pragma unroll
    for (int j = 0; j < 8; ++j){ sm += v[j]; sq += v[j]*v[j]; }
    float* redS = S; float* redQ = S + 1088;
    redS[t*33 + ci] = sm; redQ[t*33 + ci] = sq;
    __syncthreads();
    float Ssum = 0.f, Qsum = 0.f;
    #pragma unroll
    for (int k2 = 0; k2 < 32; ++k2){ Ssum += redS[t*33+k2]; Qsum += redQ[t*33+k2]; }
    float mu = Ssum*(1.f/256.f), var = Qsum*(1.f/256.f) - mu*mu;
    float r = rsqrtf(var + 1e-5f);
    float nv[8];
    #pragma unroll
    for (int j = 0; j < 8; ++j){
      int c = ci*8 + j;
      nv[j] = (v[j]-mu)*r*g[c] + bb[c];
      featT[c*36 + t] = nv[j];
    }
    if (s == 0){
      float4 o0 = {nv[0],nv[1],nv[2],nv[3]};
      float4 o1 = {nv[4],nv[5],nv[6],nv[7]};
      *(float4*)&featOut[base]     = o0;
      *(float4*)&featOut[base + 4] = o1;
    }
  }

  // ---- in_proj GEMM: 256 out-ch (128 x + 128 z), K=256 in 8 chunks of 32 ----
  int tx  = ln & 31, ch8 = (ln >> 5)*8;
  int chw = w*16 + ch8;                 // wave's 8-channel base
  float acc[8] = {};
  int cS = tid >> 2, kqS = tid & 3;
  int rowS = (cS < 128) ? (s*128 + cS) : (512 + s*128 + (cS - 128));
  const float* wrow = wip + (size_t)rowS*DM;
  for (int kc = 0; kc < 8; ++kc){
    __syncthreads();
    {
      const float4* src = (const float4*)(wrow + kc*32 + kqS*8);
      float4 u0 = src[0], u1 = src[1];
      int k0 = kqS*8;
      S[(k0+0)*264 + cS] = u0.x; S[(k0+1)*264 + cS] = u0.y;
      S[(k0+2)*264 + cS] = u0.z; S[(k0+3)*264 + cS] = u0.w;
      S[(k0+4)*264 + cS] = u1.x; S[(k0+5)*264 + cS] = u1.y;
      S[(k0+6)*264 + cS] = u1.z; S[(k0+7)*264 + cS] = u1.w;
    }
    __syncthreads();
    #pragma unroll 8
    for (int k = 0; k < 32; ++k){
      float xv = featT[(kc*32 + k)*36 + tx];
      const float* Wp = &S[k*264 + chw];
      vf4 w0 = *(const vf4*)Wp;
      vf4 w1 = *(const vf4*)(Wp + 4);
      acc[0] += xv*w0[0]; acc[1] += xv*w0[1]; acc[2] += xv*w0[2]; acc[3] += xv*w0[3];
      acc[4] += xv*w1[0]; acc[5] += xv*w1[1]; acc[6] += xv*w1[2]; acc[7] += xv*w1[3];
    }
  }
  __syncthreads();
  {
    vf4 o0 = {acc[0],acc[1],acc[2],acc[3]};
    vf4 o1 = {acc[4],acc[5],acc[6],acc[7]};
    *(vf4*)&sxz[tx*264 + chw]     = o0;
    *(vf4*)&sxz[tx*264 + chw + 4] = o1;
  }
  __syncthreads();

  // ---- conv+silu (x-half) and silu (z-half); xcl to LDS; xc/zs to global ----
  {
    int t = tid >> 5, dq = tid & 31;   // 4 channels each, stride 32
    size_t off = (size_t)(b*32 + t)*DI + s*128 + dq;
    #pragma unroll
    for (int j = 0; j < 4; ++j){
      int dl = dq + 32*j;
      int d  = s*128 + dl;
      float4 k4 = *(const float4*)(cwl + (size_t)d*4);
      float a = cbl[d];
      if (t >= 3) a += k4.x * sxz[(t-3)*264 + dl];
      if (t >= 2) a += k4.y * sxz[(t-2)*264 + dl];
      if (t >= 1) a += k4.z * sxz[(t-1)*264 + dl];
      a += k4.w * sxz[t*264 + dl];
      float rx = silu_(a);
      float rz = silu_(sxz[t*264 + 128 + dl]);
      S[t*133 + dl] = rx;               // xcl
      xc[off + 32*j] = rx;
      zs[off + 32*j] = rz;
    }
  }
  __syncthreads();

  // ---- x_proj partials over this block's 128 dims: 16 waves x 3 channels ----
  {
    int tx2 = ln >> 1, kh = ln & 1;
    #pragma unroll
    for (int j = 0; j < 3; ++j){
      int c = w*3 + j;
      const float* wr = xpl + (size_t)c*DI + s*128 + kh*64;
      const float* xr = S + tx2*133 + kh*64;
      float pa = 0.f;
      #pragma unroll 8
      for (int q = 0; q < 64; ++q) pa += wr[q]*xr[q];
      pa += __shfl_xor(pa, 1, 64);
      if (kh == 0) pxp[((size_t)(b*4 + s)*48 + c)*32 + tx2] = pa;
    }
  }
}

// ---------------- L2: x_proj reduce + dt + scan + gate + out_proj partial ----
// grid 64 = (b, s); block owns d-slice [s*128, s*128+128)
__global__ __launch_bounds__(1024, 1)
void k_L2(const float* __restrict__ pxp,
          const float* __restrict__ dtwl, const float* __restrict__ dtbl,
          const float* __restrict__ alogl, const float* __restrict__ dprl,
          const float* __restrict__ opwl,   // [256][512]
          const float* __restrict__ xc, const float* __restrict__ zs,
          float* __restrict__ parts)        // [4][512][256]
{
  extern __shared__ float lds[];
  float* sdtr = lds;             // [32][18]
  float* sB   = lds + 576;
  float* sC   = lds + 1152;
  float* sdt  = lds + 1728;      // [32][132]
  float* sxv  = lds + 5952;
  float* szz  = lds + 10176;
  float* ygT  = lds + 14400;     // [128][36]
  float* Wcp  = lds + 19008;     // [128][68]
  int tid = threadIdx.x, bid = blockIdx.x;
  int b = bid & 15, s = bid >> 4;

  // ---- sum 4 x_proj partials -> dtr/B/C ----
  if (tid < 768){
    #pragma unroll
    for (int r = 0; r < 2; ++r){
      int idx = r*768 + tid;     // c*32 + t
      int c = idx >> 5, t = idx & 31;
      size_t p0 = ((size_t)(b*4)*48 + c)*32 + t;
      float v = pxp[p0] + pxp[p0 + 1536] + pxp[p0 + 3072] + pxp[p0 + 4608];
      if      (c < 16) sdtr[t*18 + c] = v;
      else if (c < 32) sB[t*18 + (c-16)] = v;
      else             sC[t*18 + (c-32)] = v;
    }
  }
  // ---- stage xv (xc slice) and zz (silu'd z slice) ----
  {
    int t = tid >> 5, dq = tid & 31;
    size_t off = (size_t)(b*32 + t)*DI + s*128 + dq;
    #pragma unroll
    for (int j = 0; j < 4; ++j){
      sxv[t*132 + dq + 32*j] = xc[off + 32*j];
      szz[t*132 + dq + 32*j] = zs[off + 32*j];
    }
  }
  __syncthreads();

  // ---- dt = softplus(dtr @ dtw.T + dtb) for this block's 128 dims ----
  {
    int dl = tid & 127, tq = tid >> 7;
    int d = s*128 + dl;
    const float4* dwr = (const float4*)(dtwl + (size_t)d*16);
    float4 a0 = dwr[0], a1 = dwr[1], a2 = dwr[2], a3 = dwr[3];
    float bsv = dtbl[d];
    #pragma unroll
    for (int tt2 = 0; tt2 < 4; ++tt2){
      int t = tq*4 + tt2;
      const float* sr = &sdtr[t*18];
      float a = bsv;
      a += a0.x*sr[0] + a0.y*sr[1] + a0.z*sr[2] + a0.w*sr[3];
      a += a1.x*sr[4] + a1.y*sr[5] + a1.z*sr[6] + a1.w*sr[7];
      a += a2.x*sr[8] + a2.y*sr[9] + a2.z*sr[10]+ a2.w*sr[11];
      a += a3.x*sr[12]+ a3.y*sr[13]+ a3.z*sr[14]+ a3.w*sr[15];
      sdt[t*132 + dl] = fmaxf(a, 0.f) + log1pf(expf(-fabsf(a)));
    }
  }
  __syncthreads();

  // ---- selective scan + D-skip + gate -> ygT [k][t] ----
  {
    int dl = tid >> 3, ng = tid & 7;
    int d = s*128 + dl;
    int n0 = ng*2;
    float A0 = -expf(alogl[(size_t)d*16 + n0]);
    float A1 = -expf(alogl[(size_t)d*16 + n0 + 1]);
    float Dp = dprl[d];
    float h0 = 0.f, h1 = 0.f;
    for (int t = 0; t < TT; ++t){
      float dtv = sdt[t*132 + dl];
      float xv  = sxv[t*132 + dl];
      float dx = dtv*xv;
      h0 = __expf(dtv*A0)*h0 + dx*sB[t*18 + n0];
      h1 = __expf(dtv*A1)*h1 + dx*sB[t*18 + n0 + 1];
      float yv = h0*sC[t*18 + n0] + h1*sC[t*18 + n0 + 1];
      yv += __shfl_xor(yv, 1, 64);
      yv += __shfl_xor(yv, 2, 64);
      yv += __shfl_xor(yv, 4, 64);
      if (ng == 0) ygT[dl*36 + t] = (yv + Dp*xv) * szz[t*132 + dl];
    }
  }
  __syncthreads();

  // ---- out_proj partial over this block's 128 k-dims: 4 chunks of 64 out ----
  {
    int c2 = tid >> 4, kq = tid & 15;
    int tx = tid & 31, cp = tid >> 5;
    for (int cn = 0; cn < 4; ++cn){
      __syncthreads();
      {
        const float4* src = (const float4*)(opwl + (size_t)(cn*64 + c2)*DI + s*128 + kq*8);
        float4 u0 = src[0], u1 = src[1];
        int k0 = kq*8;
        Wcp[(k0+0)*68 + c2] = u0.x; Wcp[(k0+1)*68 + c2] = u0.y;
        Wcp[(k0+2)*68 + c2] = u0.z; Wcp[(k0+3)*68 + c2] = u0.w;
        Wcp[(k0+4)*68 + c2] = u1.x; Wcp[(k0+5)*68 + c2] = u1.y;
        Wcp[(k0+6)*68 + c2] = u1.z; Wcp[(k0+7)*68 + c2] = u1.w;
      }
      __syncthreads();
      float a0 = 0.f, a1 = 0.f;
      #pragma unroll 8
      for (int k = 0; k < 128; ++k){
        float xv = ygT[k*36 + tx];
        float2 wv = *(const float2*)&Wcp[k*68 + cp*2];
        a0 += xv*wv.x; a1 += xv*wv.y;
      }
      size_t po = (size_t)s*NTOK*DM + (size_t)(b*32 + tx)*DM + cn*64 + cp*2;
      *(float2*)&parts[po] = {a0, a1};
    }
  }
}

// ---------------- CLS: final residual+LN (token 31) + classifier -------------
__global__ __launch_bounds__(128)
void k_cls(const float* __restrict__ feat3, const float* __restrict__ parts,
           const float* __restrict__ ng, const float* __restrict__ nb,
           const float* __restrict__ w1, const float* __restrict__ b1,
           const float* __restrict__ w2, const float* __restrict__ b2,
           float* __restrict__ out)
{
  __shared__ float h[256];
  __shared__ float h1[128];
  int b = blockIdx.x, tid = threadIdx.x;
  if (tid < 64){
    int c4 = tid*4;
    size_t base = (size_t)(b*32 + 31)*DM + c4;
    float4 v = *(const float4*)&feat3[base];
    #pragma unroll
    for (int q = 0; q < 4; ++q){
      float4 u = *(const float4*)&parts[(size_t)q*NTOK*DM + base];
      v.x += u.x; v.y += u.y; v.z += u.z; v.w += u.w;
    }
    float sm = v.x+v.y+v.z+v.w;
    float sq = v.x*v.x+v.y*v.y+v.z*v.z+v.w*v.w;
    #pragma unroll
    for (int o = 1; o < 64; o <<= 1){ sm += __shfl_xor(sm, o, 64); sq += __shfl_xor(sq, o, 64); }
    float mu = sm*(1.f/256.f), var = sq*(1.f/256.f) - mu*mu;
    float r = rsqrtf(var + 1e-5f);
    h[c4+0] = (v.x-mu)*r*ng[c4+0] + nb[c4+0];
    h[c4+1] = (v.y-mu)*r*ng[c4+1] + nb[c4+1];
    h[c4+2] = (v.z-mu)*r*ng[c4+2] + nb[c4+2];
    h[c4+3] = (v.w-mu)*r*ng[c4+3] + nb[c4+3];
  }
  __syncthreads();
  {
    float a = b1[tid];
    const float* wr = w1 + (size_t)tid*256;
    #pragma unroll 8
    for (int j = 0; j < 256; ++j) a += h[j]*wr[j];
    h1[tid] = fmaxf(a, 0.f);
  }
  __syncthreads();
  if (tid < 2){
    float a2 = b2[tid];
    const float* wr2 = w2 + (size_t)tid*128;
    #pragma unroll 8
    for (int j = 0; j < 128; ++j) a2 += h1[j]*wr2[j];
    out[b*2 + tid] = a2;
  }
}

extern "C" void kernel_launch(void* const* d_in, const int* in_sizes, int n_in,
                              void* d_out, int out_size, void* d_ws, size_t ws_size,
                              hipStream_t stream)
{
  const float* x   = (const float*)d_in[0];
  const float* ep  = (const float*)d_in[1];
  const float* ef  = (const float*)d_in[2];
  const float* ed  = (const float*)d_in[3];
  const float* plw = (const float*)d_in[4];
  const float* plb = (const float*)d_in[5];
  const float* piw = (const float*)d_in[6];
  const float* pib = (const float*)d_in[7];
  const float* fw  = (const float*)d_in[8];
  const float* fb  = (const float*)d_in[9];
  const float* tg  = (const float*)d_in[10];
  const float* tb  = (const float*)d_in[11];
  const float* ng  = (const float*)d_in[12];
  const float* nb  = (const float*)d_in[13];
  const float* ipw = (const float*)d_in[14];
  const float* cw  = (const float*)d_in[15];
  const float* cb  = (const float*)d_in[16];
  const float* xpw = (const float*)d_in[17];
  const float* dtw = (const float*)d_in[18];
  const float* dtb = (const float*)d_in[19];
  const float* alog= (const float*)d_in[20];
  const float* dpr = (const float*)d_in[21];
  const float* opw = (const float*)d_in[22];
  const float* w1  = (const float*)d_in[23];
  const float* b1  = (const float*)d_in[24];
  const float* w2  = (const float*)d_in[25];
  const float* b2  = (const float*)d_in[26];
  (void)in_sizes; (void)n_in; (void)out_size; (void)ws_size;

  float* ws    = (float*)d_ws;
  float* fb0   = ws;                      // 131072
  float* fb1   = fb0 + NTOK*DM;           // 131072
  float* s0    = fb1 + NTOK*DM;           // 131072
  float* parts = s0  + NTOK*DM;           // 4*131072
  float* pxp   = parts + 4*NTOK*DM;       // 64*48*32 = 98304
  float* xcb   = pxp + 98304;             // 262144
  float* zsb   = xcb + NTOK*DI;           // 262144
  float* fbuf[2] = {fb0, fb1};

  const size_t L1_LDS = (size_t)26112*4;   // 104448 B
  const size_t L2_LDS = (size_t)27712*4;   // 110848 B

  k_front<<<dim3(4,16),128,0,stream>>>(x, ep,ef,ed, plw,plb,piw,pib, fw,fb, s0);
  for (int ly = 0; ly < 4; ++ly){
    const float* gg = ly ? ng : tg;
    const float* gb = ly ? nb : tb;
    const float* pin = ly ? parts : s0;
    const float* fin = ly ? fbuf[(ly+1)&1] : nullptr;
    k_L1<<<64,1024,L1_LDS,stream>>>(ipw + (size_t)ly*262144,
                                    cw + (size_t)ly*2048, cb + (size_t)ly*512,
                                    xpw + (size_t)ly*24576,
                                    gg, gb, fin, fbuf[ly&1],
                                    pin, ly ? 1 : 0,
                                    pxp, xcb, zsb);
    k_L2<<<64,1024,L2_LDS,stream>>>(pxp,
                                    dtw + (size_t)ly*8192, dtb + (size_t)ly*512,
                                    alog + (size_t)ly*8192, dpr + (size_t)ly*512,
                                    opw + (size_t)ly*131072,
                                    xcb, zsb, parts);
  }
  k_cls<<<16,128,0,stream>>>(fbuf[1], parts, ng, nb, w1, b1, w2, b2, (float*)d_out);
}